// Round 1
// baseline (2124.959 us; speedup 1.0000x reference)
//
#include <hip/hip_runtime.h>
#include <math.h>

namespace {

constexpr int kT = 1024;
constexpr int kH = 1024;
constexpr int kNQ = 16;
constexpr int kNKV = 4;
constexpr int kD = 64;
constexpr int kQKV = (kNQ + 2 * kNKV) * kD;   // 1536
constexpr int kIDense = 4096;
constexpr int kIMoe = 512;
constexpr int kE = 8;
constexpr float kEps = 1e-6f;

// ---------------------------------------------------------------------------
// fused add + RMSNorm: r_out = x + res;  h_out = rmsnorm(r_out) * w
// one block per row, 256 threads, 1 float4/thread
// ---------------------------------------------------------------------------
__global__ __launch_bounds__(256) void add_rmsnorm_kernel(
    const float* __restrict__ x, const float* __restrict__ res,
    const float* __restrict__ w, float* __restrict__ h_out, float* __restrict__ r_out)
{
    __shared__ float red[4];
    const int t = blockIdx.x;
    const int i = threadIdx.x;
    const size_t base = (size_t)t * kH;
    float4 a = reinterpret_cast<const float4*>(x + base)[i];
    float4 b = reinterpret_cast<const float4*>(res + base)[i];
    float4 s = make_float4(a.x + b.x, a.y + b.y, a.z + b.z, a.w + b.w);
    reinterpret_cast<float4*>(r_out + base)[i] = s;
    float ss = s.x * s.x + s.y * s.y + s.z * s.z + s.w * s.w;
    #pragma unroll
    for (int off = 32; off > 0; off >>= 1) ss += __shfl_down(ss, off);
    if ((i & 63) == 0) red[i >> 6] = ss;
    __syncthreads();
    const float tot = red[0] + red[1] + red[2] + red[3];
    const float inv = rsqrtf(tot * (1.0f / kH) + kEps);
    float4 wv = reinterpret_cast<const float4*>(w)[i];
    float4 o = make_float4(s.x * inv * wv.x, s.y * inv * wv.y,
                           s.z * inv * wv.z, s.w * inv * wv.w);
    reinterpret_cast<float4*>(h_out + base)[i] = o;
}

// ---------------------------------------------------------------------------
// f32 tiled GEMM: C = A(M x K, row-major, lda=K) @ B(K x N, row stride ldb)
// 64x64 tile, BK=16, 256 threads, 4x4 microtile.
// GATED: C[:,j] = silu(A.Bg[:,j]) * (A.Bu[:,j+gate_off]) * scale[row]
// blockIdx.z batches B (b_batch_stride) and offsets C columns (c_batch_col).
// ---------------------------------------------------------------------------
template <bool GATED>
__global__ __launch_bounds__(256) void gemm_kernel(
    const float* __restrict__ A, const float* __restrict__ B, float* __restrict__ C,
    int K, int ldb, int ldc, int gate_off,
    size_t b_batch_stride, int c_batch_col,
    const float* __restrict__ scale, int scale_stride)
{
    __shared__ float As[16][68];                 // pad 68 -> conflict-free
    __shared__ float Bg[16][64];
    __shared__ float Bu[GATED ? 16 : 1][64];
    const int z = blockIdx.z;
    const float* Bz = B + (size_t)z * b_batch_stride;
    float* Cz = C + (size_t)z * c_batch_col;
    const int m0 = blockIdx.y * 64;
    const int n0 = blockIdx.x * 64;
    const int tid = threadIdx.x;
    const int al_k = tid & 15;
    const int al_m = tid >> 4;
    const int bl_n = tid & 63;
    const int bl_k = tid >> 6;
    const int tr = tid >> 4;
    const int tc = tid & 15;
    float accg[4][4] = {};
    float accu[4][4] = {};
    const float* Ap = A + (size_t)(m0 + al_m) * K + al_k;
    const float* Bp = Bz + (size_t)bl_k * ldb + n0 + bl_n;

    for (int k0 = 0; k0 < K; k0 += 16) {
        #pragma unroll
        for (int mm = 0; mm < 4; mm++)
            As[al_k][al_m + mm * 16] = Ap[(size_t)(mm * 16) * K + k0];
        #pragma unroll
        for (int kk = 0; kk < 4; kk++) {
            const size_t boff = (size_t)(k0 + kk * 4) * ldb;
            Bg[bl_k + kk * 4][bl_n] = Bp[boff];
            if constexpr (GATED) Bu[bl_k + kk * 4][bl_n] = Bp[boff + gate_off];
        }
        __syncthreads();
        #pragma unroll
        for (int kk = 0; kk < 16; kk++) {
            float4 a4 = *reinterpret_cast<const float4*>(&As[kk][tr * 4]);
            float4 g4 = *reinterpret_cast<const float4*>(&Bg[kk][tc * 4]);
            float av[4] = {a4.x, a4.y, a4.z, a4.w};
            float gv[4] = {g4.x, g4.y, g4.z, g4.w};
            if constexpr (GATED) {
                float4 u4 = *reinterpret_cast<const float4*>(&Bu[kk][tc * 4]);
                float uv[4] = {u4.x, u4.y, u4.z, u4.w};
                #pragma unroll
                for (int i = 0; i < 4; i++) {
                    #pragma unroll
                    for (int j = 0; j < 4; j++) {
                        accg[i][j] += av[i] * gv[j];
                        accu[i][j] += av[i] * uv[j];
                    }
                }
            } else {
                #pragma unroll
                for (int i = 0; i < 4; i++) {
                    #pragma unroll
                    for (int j = 0; j < 4; j++) accg[i][j] += av[i] * gv[j];
                }
            }
        }
        __syncthreads();
    }

    #pragma unroll
    for (int i = 0; i < 4; i++) {
        const int row = m0 + tr * 4 + i;
        float sv = 1.0f;
        if constexpr (GATED) {
            if (scale != nullptr) sv = scale[(size_t)row * scale_stride + z];
        }
        #pragma unroll
        for (int j = 0; j < 4; j++) {
            float v;
            if constexpr (GATED) {
                const float g = accg[i][j];
                const float u = accu[i][j];
                v = (g / (1.0f + expf(-g))) * u * sv;   // silu(g)*u
            } else {
                v = accg[i][j];
            }
            Cz[(size_t)row * ldc + n0 + tc * 4 + j] = v;
        }
    }
}

// ---------------------------------------------------------------------------
// RoPE in-place on qkv buffer rows: heads 0..19 (16 q + 4 k) are contiguous
// 64-wide slots; pair (i, i+32) rotated by angle pos * 10000^(-i/32).
// ---------------------------------------------------------------------------
__global__ __launch_bounds__(256) void rope_kernel(
    float* __restrict__ qkv, const int* __restrict__ positions)
{
    const int t = blockIdx.x;
    const float pos = (float)positions[t];
    for (int item = threadIdx.x; item < (kNQ + kNKV) * 32; item += 256) {
        const int head = item >> 5;
        const int i = item & 31;
        const float inv_freq = 1.0f / powf(10000.0f, (float)i * (1.0f / 32.0f));
        const float f = pos * inv_freq;
        float sv, cv;
        sincosf(f, &sv, &cv);
        const size_t off = (size_t)t * kQKV + head * kD;
        const float x1 = qkv[off + i];
        const float x2 = qkv[off + 32 + i];
        qkv[off + i] = x1 * cv - x2 * sv;
        qkv[off + 32 + i] = x2 * cv + x1 * sv;
    }
}

// ---------------------------------------------------------------------------
// Router: logits = h @ gate_w (H x 8), softmax, top-2 -> combine (T x 8)
// one wave per row
// ---------------------------------------------------------------------------
__global__ __launch_bounds__(64) void gate_topk_kernel(
    const float* __restrict__ h, const float* __restrict__ gate_w,
    float* __restrict__ combine)
{
    const int t = blockIdx.x;
    const int lane = threadIdx.x;
    float acc[kE] = {};
    for (int i = lane; i < kH; i += 64) {
        const float xv = h[(size_t)t * kH + i];
        const float* gw = gate_w + (size_t)i * kE;
        #pragma unroll
        for (int e = 0; e < kE; e++) acc[e] += xv * gw[e];
    }
    #pragma unroll
    for (int e = 0; e < kE; e++) {
        #pragma unroll
        for (int off = 32; off > 0; off >>= 1) acc[e] += __shfl_down(acc[e], off);
    }
    if (lane == 0) {
        float mx = acc[0];
        #pragma unroll
        for (int e = 1; e < kE; e++) mx = fmaxf(mx, acc[e]);
        float p[kE];
        float s = 0.0f;
        #pragma unroll
        for (int e = 0; e < kE; e++) { p[e] = expf(acc[e] - mx); s += p[e]; }
        const float invs = 1.0f / s;
        #pragma unroll
        for (int e = 0; e < kE; e++) p[e] *= invs;
        int i1 = 0;
        #pragma unroll
        for (int e = 1; e < kE; e++) if (p[e] > p[i1]) i1 = e;       // first max
        int i2 = (i1 == 0) ? 1 : 0;
        #pragma unroll
        for (int e = 0; e < kE; e++) if (e != i1 && p[e] > p[i2]) i2 = e;
        float outv[kE];
        #pragma unroll
        for (int e = 0; e < kE; e++) outv[e] = 0.0f;
        outv[i1] = p[i1];
        outv[i2] = p[i2];
        #pragma unroll
        for (int e = 0; e < kE; e++) combine[(size_t)t * kE + e] = outv[e];
    }
}

// ---------------------------------------------------------------------------
// Flash-style causal GQA attention, f32. Block = (q-tile of 64 rows, 1 q head).
// Tiles of 64 keys; scores + P staged in LDS to decouple thread mappings.
// ---------------------------------------------------------------------------
constexpr int kAP = 68;   // padded LDS row stride (floats), keeps f4 alignment

__global__ __launch_bounds__(256) void attn_kernel(
    const float* __restrict__ qkv, float* __restrict__ attn_o)
{
    __shared__ float Qs[64 * kAP];
    __shared__ float Ks[64 * kAP];
    __shared__ float Vs[64 * kAP];
    __shared__ float Ps[64 * kAP];
    __shared__ float alphaS[64];
    __shared__ float lS[64];
    const int tid = threadIdx.x;
    const int qb = blockIdx.x * 64;
    const int hq = blockIdx.y;
    const int kvh = hq >> 2;                    // group size 4
    const int ldr = tid >> 2;                   // load: row 0..63
    const int ldd = (tid & 3) * 16;             // load: col base
    const int sr = tid >> 4;                    // compute: 4-row group 0..15
    const int sc = tid & 15;                    // compute: 4-col group 0..15
    const int mr = tid >> 2;                    // softmax: row 0..63
    const int mc = (tid & 3) * 16;              // softmax: col base

    {   // load Q tile, pre-scaled by D^-1/2
        const float4* src = reinterpret_cast<const float4*>(
            qkv + (size_t)(qb + ldr) * kQKV + hq * kD + ldd);
        float4* dst = reinterpret_cast<float4*>(&Qs[ldr * kAP + ldd]);
        #pragma unroll
        for (int jj = 0; jj < 4; jj++) {
            float4 v = src[jj];
            v.x *= 0.125f; v.y *= 0.125f; v.z *= 0.125f; v.w *= 0.125f;
            dst[jj] = v;
        }
    }
    float oacc[4][4] = {};
    float m = -1e30f, l = 0.0f;

    for (int s0 = 0; s0 <= qb; s0 += 64) {
        __syncthreads();   // previous iter done with Ks/Vs/Ps
        {   // load K, V tiles
            const float4* ksrc = reinterpret_cast<const float4*>(
                qkv + (size_t)(s0 + ldr) * kQKV + (kNQ * kD) + kvh * kD + ldd);
            const float4* vsrc = reinterpret_cast<const float4*>(
                qkv + (size_t)(s0 + ldr) * kQKV + ((kNQ + kNKV) * kD) + kvh * kD + ldd);
            float4* kdst = reinterpret_cast<float4*>(&Ks[ldr * kAP + ldd]);
            float4* vdst = reinterpret_cast<float4*>(&Vs[ldr * kAP + ldd]);
            #pragma unroll
            for (int jj = 0; jj < 4; jj++) { kdst[jj] = ksrc[jj]; vdst[jj] = vsrc[jj]; }
        }
        __syncthreads();

        // ---- scores S = Q K^T (4x4 per thread), masked, -> Ps
        float sacc[4][4] = {};
        #pragma unroll
        for (int d4 = 0; d4 < 16; d4++) {
            float qv[4][4], kv[4][4];
            #pragma unroll
            for (int i = 0; i < 4; i++) {
                float4 q4 = *reinterpret_cast<const float4*>(&Qs[(sr * 4 + i) * kAP + d4 * 4]);
                qv[i][0] = q4.x; qv[i][1] = q4.y; qv[i][2] = q4.z; qv[i][3] = q4.w;
            }
            #pragma unroll
            for (int j = 0; j < 4; j++) {
                float4 k4 = *reinterpret_cast<const float4*>(&Ks[(sc * 4 + j) * kAP + d4 * 4]);
                kv[j][0] = k4.x; kv[j][1] = k4.y; kv[j][2] = k4.z; kv[j][3] = k4.w;
            }
            #pragma unroll
            for (int i = 0; i < 4; i++) {
                #pragma unroll
                for (int j = 0; j < 4; j++) {
                    float a = sacc[i][j];
                    #pragma unroll
                    for (int d = 0; d < 4; d++) a += qv[i][d] * kv[j][d];
                    sacc[i][j] = a;
                }
            }
        }
        #pragma unroll
        for (int i = 0; i < 4; i++) {
            const int trow = qb + sr * 4 + i;
            #pragma unroll
            for (int j = 0; j < 4; j++) {
                const int scol = s0 + sc * 4 + j;
                Ps[(sr * 4 + i) * kAP + sc * 4 + j] = (scol <= trow) ? sacc[i][j] : -1e30f;
            }
        }
        __syncthreads();

        // ---- online softmax on rows (4 threads/row share via shfl)
        float pv[16];
        float mloc = -1e30f;
        #pragma unroll
        for (int j4 = 0; j4 < 4; j4++) {
            float4 v4 = *reinterpret_cast<const float4*>(&Ps[mr * kAP + mc + j4 * 4]);
            pv[j4 * 4 + 0] = v4.x; pv[j4 * 4 + 1] = v4.y;
            pv[j4 * 4 + 2] = v4.z; pv[j4 * 4 + 3] = v4.w;
            mloc = fmaxf(mloc, fmaxf(fmaxf(v4.x, v4.y), fmaxf(v4.z, v4.w)));
        }
        mloc = fmaxf(mloc, __shfl_xor(mloc, 1));
        mloc = fmaxf(mloc, __shfl_xor(mloc, 2));
        const float mnew = fmaxf(m, mloc);
        const float alpha = __expf(m - mnew);
        float psum = 0.0f;
        #pragma unroll
        for (int j = 0; j < 16; j++) {
            const float p = __expf(pv[j] - mnew);
            pv[j] = p;
            psum += p;
        }
        psum += __shfl_xor(psum, 1);
        psum += __shfl_xor(psum, 2);
        l = l * alpha + psum;
        m = mnew;
        #pragma unroll
        for (int j4 = 0; j4 < 4; j4++) {
            *reinterpret_cast<float4*>(&Ps[mr * kAP + mc + j4 * 4]) =
                make_float4(pv[j4 * 4 + 0], pv[j4 * 4 + 1], pv[j4 * 4 + 2], pv[j4 * 4 + 3]);
        }
        if ((tid & 3) == 0) alphaS[mr] = alpha;
        __syncthreads();

        // ---- O = O*alpha + P @ V (4x4 per thread)
        #pragma unroll
        for (int i = 0; i < 4; i++) {
            const float al = alphaS[sr * 4 + i];
            #pragma unroll
            for (int j = 0; j < 4; j++) oacc[i][j] *= al;
        }
        #pragma unroll
        for (int k4 = 0; k4 < 16; k4++) {
            float pvv[4][4], vvv[4][4];
            #pragma unroll
            for (int i = 0; i < 4; i++) {
                float4 p4 = *reinterpret_cast<const float4*>(&Ps[(sr * 4 + i) * kAP + k4 * 4]);
                pvv[i][0] = p4.x; pvv[i][1] = p4.y; pvv[i][2] = p4.z; pvv[i][3] = p4.w;
            }
            #pragma unroll
            for (int kk = 0; kk < 4; kk++) {
                float4 v4 = *reinterpret_cast<const float4*>(&Vs[(k4 * 4 + kk) * kAP + sc * 4]);
                vvv[kk][0] = v4.x; vvv[kk][1] = v4.y; vvv[kk][2] = v4.z; vvv[kk][3] = v4.w;
            }
            #pragma unroll
            for (int i = 0; i < 4; i++) {
                #pragma unroll
                for (int j = 0; j < 4; j++) {
                    float a = oacc[i][j];
                    #pragma unroll
                    for (int kk = 0; kk < 4; kk++) a += pvv[i][kk] * vvv[kk][j];
                    oacc[i][j] = a;
                }
            }
        }
    }

    if ((tid & 3) == 0) lS[mr] = l;
    __syncthreads();
    #pragma unroll
    for (int i = 0; i < 4; i++) {
        const float inv = 1.0f / lS[sr * 4 + i];
        #pragma unroll
        for (int j = 0; j < 4; j++)
            attn_o[(size_t)(qb + sr * 4 + i) * (kNQ * kD) + hq * kD + sc * 4 + j] =
                oacc[i][j] * inv;
    }
}

// ---------------------------------------------------------------------------
// final: out[0:T*H] = mlp + shortcut ; out[T*H:2*T*H] = r
// ---------------------------------------------------------------------------
__global__ __launch_bounds__(256) void final_out_kernel(
    const float* __restrict__ mlp, const float* __restrict__ shortcut,
    const float* __restrict__ r, float* __restrict__ out)
{
    const int i = blockIdx.x * 256 + threadIdx.x;    // float4 index
    float4 a = reinterpret_cast<const float4*>(mlp)[i];
    float4 b = reinterpret_cast<const float4*>(shortcut)[i];
    reinterpret_cast<float4*>(out)[i] =
        make_float4(a.x + b.x, a.y + b.y, a.z + b.z, a.w + b.w);
    reinterpret_cast<float4*>(out + (size_t)kT * kH)[i] =
        reinterpret_cast<const float4*>(r)[i];
}

}  // namespace

extern "C" void kernel_launch(void* const* d_in, const int* in_sizes, int n_in,
                              void* d_out, int out_size, void* d_ws, size_t ws_size,
                              hipStream_t stream) {
    (void)in_sizes; (void)n_in; (void)out_size; (void)ws_size;
    const float* hidden   = (const float*)d_in[0];
    const float* residual = (const float*)d_in[1];
    const int*   positions= (const int*)d_in[2];
    const float* ln0_w    = (const float*)d_in[3];
    const float* pa0_w    = (const float*)d_in[4];
    const float* ln1_w    = (const float*)d_in[5];
    const float* pa1_w    = (const float*)d_in[6];
    const float* qkv0_w   = (const float*)d_in[7];
    const float* o0_w     = (const float*)d_in[8];
    const float* qkv1_w   = (const float*)d_in[9];
    const float* o1_w     = (const float*)d_in[10];
    const float* gu0_w    = (const float*)d_in[11];
    const float* dn0_w    = (const float*)d_in[12];
    const float* gu1_w    = (const float*)d_in[13];
    const float* dn1_w    = (const float*)d_in[14];
    const float* gate_w   = (const float*)d_in[15];
    const float* w13      = (const float*)d_in[16];
    const float* w2       = (const float*)d_in[17];
    float* out_h = (float*)d_out;

    // workspace layout (floats); qkv+attn_o alias the He region (disjoint in time)
    float* ws      = (float*)d_ws;
    float* r_buf   = ws;                         // T*H
    float* h_buf   = ws + 1 * 1048576;           // T*H
    float* t0_buf  = ws + 2 * 1048576;           // T*H
    float* region  = ws + 3 * 1048576;           // 4M floats shared
    float* qkv_buf = region;                     // T*1536
    float* ao_buf  = region + (size_t)kT * kQKV; // T*1024
    float* he_buf  = region;                     // T*4096
    float* sc_buf  = ws + 7 * 1048576;           // T*H (MoE shortcut)
    float* cb_buf  = ws + 8 * 1048576;           // T*8 combine

    auto gemm = [&](const float* A, const float* Bp, float* Cp, int M, int N, int K,
                    int ldb, int ldc) {
        gemm_kernel<false><<<dim3(N / 64, M / 64, 1), 256, 0, stream>>>(
            A, Bp, Cp, K, ldb, ldc, 0, 0, 0, nullptr, 0);
    };
    auto attention = [&](const float* qkv_w, const float* o_w) {
        gemm(h_buf, qkv_w, qkv_buf, kT, kQKV, kH, kQKV, kQKV);
        rope_kernel<<<kT, 256, 0, stream>>>(qkv_buf, positions);
        attn_kernel<<<dim3(kT / 64, kNQ), 256, 0, stream>>>(qkv_buf, ao_buf);
        gemm(ao_buf, o_w, t0_buf, kT, kH, kNQ * kD, kH, kH);
    };

    // h, r = add_rmsnorm(hidden, residual, ln0)
    add_rmsnorm_kernel<<<kT, 256, 0, stream>>>(hidden, residual, ln0_w, h_buf, r_buf);
    // h = attention0(h)
    attention(qkv0_w, o0_w);
    // h, r = add_rmsnorm(h, r, pa0)
    add_rmsnorm_kernel<<<kT, 256, 0, stream>>>(t0_buf, r_buf, pa0_w, h_buf, r_buf);
    // shortcut = moe(h)
    gate_topk_kernel<<<kT, 64, 0, stream>>>(h_buf, gate_w, cb_buf);
    gemm_kernel<true><<<dim3(kIMoe / 64, kT / 64, kE), 256, 0, stream>>>(
        h_buf, w13, he_buf, kH, 2 * kIMoe, kIDense, kIMoe,
        (size_t)kH * 2 * kIMoe, kIMoe, cb_buf, kE);
    gemm(he_buf, w2, sc_buf, kT, kH, kIDense, kH, kH);
    // h = dense_mlp0(h)
    gemm_kernel<true><<<dim3(kIDense / 64, kT / 64, 1), 256, 0, stream>>>(
        h_buf, gu0_w, he_buf, kH, 2 * kIDense, kIDense, kIDense, 0, 0, nullptr, 0);
    gemm(he_buf, dn0_w, t0_buf, kT, kH, kIDense, kH, kH);
    // h, r = add_rmsnorm(h, r, ln1)
    add_rmsnorm_kernel<<<kT, 256, 0, stream>>>(t0_buf, r_buf, ln1_w, h_buf, r_buf);
    // h = attention1(h)
    attention(qkv1_w, o1_w);
    // h, r = add_rmsnorm(h, r, pa1)
    add_rmsnorm_kernel<<<kT, 256, 0, stream>>>(t0_buf, r_buf, pa1_w, h_buf, r_buf);
    // h = dense_mlp1(h)
    gemm_kernel<true><<<dim3(kIDense / 64, kT / 64, 1), 256, 0, stream>>>(
        h_buf, gu1_w, he_buf, kH, 2 * kIDense, kIDense, kIDense, 0, 0, nullptr, 0);
    gemm(he_buf, dn1_w, t0_buf, kT, kH, kIDense, kH, kH);
    // out = (h + shortcut, r)
    final_out_kernel<<<(kT * kH / 4) / 256, 256, 0, stream>>>(t0_buf, sc_buf, r_buf, out_h);
}

// Round 2
// 792.265 us; speedup vs baseline: 2.6821x; 2.6821x over previous
//
#include <hip/hip_runtime.h>
#include <math.h>

namespace {

constexpr int kT = 1024;
constexpr int kH = 1024;
constexpr int kNQ = 16;
constexpr int kNKV = 4;
constexpr int kD = 64;
constexpr int kQKV = (kNQ + 2 * kNKV) * kD;   // 1536
constexpr int kIDense = 4096;
constexpr int kIMoe = 512;
constexpr int kE = 8;
constexpr float kEps = 1e-6f;

typedef __attribute__((ext_vector_type(8))) short short8;
typedef __attribute__((ext_vector_type(4))) float f32x4;

__device__ __forceinline__ ushort f2bf(float f) {
    union { float f; uint32_t u; } v; v.f = f;
    uint32_t r = (v.u + 0x7fffu + ((v.u >> 16) & 1u)) >> 16;
    return (ushort)r;
}
__device__ __forceinline__ float bf2f(ushort b) {
    union { uint32_t u; float f; } v; v.u = ((uint32_t)b) << 16;
    return v.f;
}
__device__ __forceinline__ void gload16(const void* g, void* l) {
    __builtin_amdgcn_global_load_lds(
        (const __attribute__((address_space(1))) void*)g,
        (__attribute__((address_space(3))) void*)l, 16, 0, 0);
}

// ---------------------------------------------------------------------------
// add + RMSNorm: r_out = x + res; h = rmsnorm(r_out)*w  -> h32 (f32) + h16 (bf16)
// ---------------------------------------------------------------------------
__global__ __launch_bounds__(256) void add_rmsnorm_kernel(
    const float* __restrict__ x, const float* __restrict__ res,
    const float* __restrict__ w, float* __restrict__ h32,
    ushort* __restrict__ h16, float* __restrict__ r_out)
{
    __shared__ float red[4];
    const int t = blockIdx.x;
    const int i = threadIdx.x;
    const size_t base = (size_t)t * kH;
    float4 a = reinterpret_cast<const float4*>(x + base)[i];
    float4 b = reinterpret_cast<const float4*>(res + base)[i];
    float4 s = make_float4(a.x + b.x, a.y + b.y, a.z + b.z, a.w + b.w);
    reinterpret_cast<float4*>(r_out + base)[i] = s;
    float ss = s.x * s.x + s.y * s.y + s.z * s.z + s.w * s.w;
    #pragma unroll
    for (int off = 32; off > 0; off >>= 1) ss += __shfl_down(ss, off);
    if ((i & 63) == 0) red[i >> 6] = ss;
    __syncthreads();
    const float tot = red[0] + red[1] + red[2] + red[3];
    const float inv = rsqrtf(tot * (1.0f / kH) + kEps);
    float4 wv = reinterpret_cast<const float4*>(w)[i];
    float4 o = make_float4(s.x * inv * wv.x, s.y * inv * wv.y,
                           s.z * inv * wv.z, s.w * inv * wv.w);
    reinterpret_cast<float4*>(h32 + base)[i] = o;
    ushort4 u;
    u.x = f2bf(o.x); u.y = f2bf(o.y); u.z = f2bf(o.z); u.w = f2bf(o.w);
    reinterpret_cast<ushort4*>(h16 + base)[i] = u;
}

// ---------------------------------------------------------------------------
// transpose + f32 -> bf16: W (R x Cn f32, row-major) -> WT (Cn x R bf16)
// 64x64 tiles; batched via blockIdx.z.
// ---------------------------------------------------------------------------
__global__ __launch_bounds__(256) void transpose_bf16_kernel(
    const float* __restrict__ W, ushort* __restrict__ WT,
    int R, int Cn, long w_z_stride, long wt_z_stride)
{
    __shared__ float tile[64][65];
    const int z = blockIdx.z;
    const float* Wz = W + (size_t)z * w_z_stride;
    ushort* WTz = WT + (size_t)z * wt_z_stride;
    const int r0 = blockIdx.y * 64;
    const int c0 = blockIdx.x * 64;
    const int tr = threadIdx.x >> 4;
    const int tc4 = (threadIdx.x & 15) * 4;
    #pragma unroll
    for (int p = 0; p < 4; p++) {
        float4 v = *reinterpret_cast<const float4*>(
            &Wz[(size_t)(r0 + p * 16 + tr) * Cn + c0 + tc4]);
        tile[p * 16 + tr][tc4 + 0] = v.x;
        tile[p * 16 + tr][tc4 + 1] = v.y;
        tile[p * 16 + tr][tc4 + 2] = v.z;
        tile[p * 16 + tr][tc4 + 3] = v.w;
    }
    __syncthreads();
    #pragma unroll
    for (int p = 0; p < 4; p++) {
        const int oc = p * 16 + tr;          // input col = output row
        ushort4 u;
        u.x = f2bf(tile[tc4 + 0][oc]);
        u.y = f2bf(tile[tc4 + 1][oc]);
        u.z = f2bf(tile[tc4 + 2][oc]);
        u.w = f2bf(tile[tc4 + 3][oc]);
        *reinterpret_cast<ushort4*>(&WTz[(size_t)(c0 + oc) * R + r0 + tc4]) = u;
    }
}

// ---------------------------------------------------------------------------
// bf16 MFMA GEMM, 64x64 tile, BK=64, 256 threads (4 waves, 2x2 16x16 frags).
// A: M x lda bf16 row-major. B: N x ldb bf16 row-major (i.e. weight^T).
// blockIdx.z = split-K chunk (k_z_off) OR expert batch (b_z_stride/c_z_col).
// GATED: stages gate rows [n] and up rows [gate_off_rows+n];
//        out bf16 = silu(g)*u*scale. Else: f32 out (atomicAdd if atomic_flag).
// ---------------------------------------------------------------------------
template <bool GATED>
__global__ __launch_bounds__(256) void mgemm_kernel(
    const ushort* __restrict__ A, const ushort* __restrict__ B,
    float* __restrict__ Cf, ushort* __restrict__ C16,
    const float* __restrict__ scale,
    int lda, int ldb, int ldc, int kc,
    int gate_off_rows, long b_z_stride, int c_z_col, int k_z_off,
    int scale_stride, int atomic_flag)
{
    __shared__ __align__(16) ushort As[64 * 64];
    __shared__ __align__(16) ushort Bs[64 * 64];
    __shared__ __align__(16) ushort Us[GATED ? 64 * 64 : 16];

    const int z = blockIdx.z;
    const int m0 = blockIdx.y * 64;
    const int n0 = blockIdx.x * 64;
    const int tid = threadIdx.x;
    const ushort* Bz = B + (size_t)z * b_z_stride;
    const int k0 = z * k_z_off;

    const int srow = tid >> 3;           // staging row within 32-row chunk
    const int sc8 = (tid & 7) * 8;       // staging col (elements)

    const int lane = tid & 63;
    const int wave = tid >> 6;
    const int wr = (wave >> 1) * 32;
    const int wc = (wave & 1) * 32;
    const int lrow = lane & 15;
    const int lk8 = (lane >> 4) * 8;

    f32x4 accg[2][2] = {};
    f32x4 accu[2][2] = {};

    for (int kk0 = 0; kk0 < kc; kk0 += 64) {
        const int kbase = k0 + kk0;
        #pragma unroll
        for (int i = 0; i < 2; i++) {
            gload16(A + (size_t)(m0 + i * 32 + srow) * lda + kbase + sc8,
                    (char*)As + i * 4096 + tid * 16);
            gload16(Bz + (size_t)(n0 + i * 32 + srow) * ldb + kbase + sc8,
                    (char*)Bs + i * 4096 + tid * 16);
            if constexpr (GATED)
                gload16(Bz + (size_t)(gate_off_rows + n0 + i * 32 + srow) * ldb + kbase + sc8,
                        (char*)Us + i * 4096 + tid * 16);
        }
        __syncthreads();

        short8 af[2][2], bfr[2][2];
        #pragma unroll
        for (int mf = 0; mf < 2; mf++)
            #pragma unroll
            for (int kk = 0; kk < 2; kk++)
                af[mf][kk] = *reinterpret_cast<const short8*>(
                    &As[(wr + mf * 16 + lrow) * 64 + kk * 32 + lk8]);
        #pragma unroll
        for (int nf = 0; nf < 2; nf++)
            #pragma unroll
            for (int kk = 0; kk < 2; kk++)
                bfr[nf][kk] = *reinterpret_cast<const short8*>(
                    &Bs[(wc + nf * 16 + lrow) * 64 + kk * 32 + lk8]);
        #pragma unroll
        for (int mf = 0; mf < 2; mf++)
            #pragma unroll
            for (int nf = 0; nf < 2; nf++)
                #pragma unroll
                for (int kk = 0; kk < 2; kk++)
                    accg[mf][nf] = __builtin_amdgcn_mfma_f32_16x16x32_bf16(
                        af[mf][kk], bfr[nf][kk], accg[mf][nf], 0, 0, 0);
        if constexpr (GATED) {
            short8 uf[2][2];
            #pragma unroll
            for (int nf = 0; nf < 2; nf++)
                #pragma unroll
                for (int kk = 0; kk < 2; kk++)
                    uf[nf][kk] = *reinterpret_cast<const short8*>(
                        &Us[(wc + nf * 16 + lrow) * 64 + kk * 32 + lk8]);
            #pragma unroll
            for (int mf = 0; mf < 2; mf++)
                #pragma unroll
                for (int nf = 0; nf < 2; nf++)
                    #pragma unroll
                    for (int kk = 0; kk < 2; kk++)
                        accu[mf][nf] = __builtin_amdgcn_mfma_f32_16x16x32_bf16(
                            af[mf][kk], uf[nf][kk], accu[mf][nf], 0, 0, 0);
        }
        __syncthreads();
    }

    // epilogue — C/D layout: col = lane&15, row = (lane>>4)*4 + j
    const int r4 = (lane >> 4) * 4;
    const int cl = lane & 15;
    const int ccol = z * c_z_col;
    #pragma unroll
    for (int mf = 0; mf < 2; mf++) {
        #pragma unroll
        for (int nf = 0; nf < 2; nf++) {
            #pragma unroll
            for (int j = 0; j < 4; j++) {
                const int row = m0 + wr + mf * 16 + r4 + j;
                const int col = ccol + n0 + wc + nf * 16 + cl;
                if constexpr (GATED) {
                    const float g = accg[mf][nf][j];
                    const float u = accu[mf][nf][j];
                    const float sv =
                        scale ? scale[(size_t)row * scale_stride + z] : 1.0f;
                    const float h = (g / (1.0f + __expf(-g))) * u * sv;
                    C16[(size_t)row * ldc + col] = f2bf(h);
                } else if (atomic_flag) {
                    atomicAdd(&Cf[(size_t)row * ldc + col], accg[mf][nf][j]);
                } else {
                    Cf[(size_t)row * ldc + col] = accg[mf][nf][j];
                }
            }
        }
    }
}

// ---------------------------------------------------------------------------
// RoPE in-place on qkv rows (16 q + 4 k heads)
// ---------------------------------------------------------------------------
__global__ __launch_bounds__(256) void rope_kernel(
    float* __restrict__ qkv, const int* __restrict__ positions)
{
    const int t = blockIdx.x;
    const float pos = (float)positions[t];
    for (int item = threadIdx.x; item < (kNQ + kNKV) * 32; item += 256) {
        const int head = item >> 5;
        const int i = item & 31;
        const float inv_freq = 1.0f / powf(10000.0f, (float)i * (1.0f / 32.0f));
        const float f = pos * inv_freq;
        float sv, cv;
        sincosf(f, &sv, &cv);
        const size_t off = (size_t)t * kQKV + head * kD;
        const float x1 = qkv[off + i];
        const float x2 = qkv[off + 32 + i];
        qkv[off + i] = x1 * cv - x2 * sv;
        qkv[off + 32 + i] = x2 * cv + x1 * sv;
    }
}

// ---------------------------------------------------------------------------
// Router: logits = h32 @ gate_w, softmax, top-2 -> combine (T x 8)
// ---------------------------------------------------------------------------
__global__ __launch_bounds__(64) void gate_topk_kernel(
    const float* __restrict__ h, const float* __restrict__ gate_w,
    float* __restrict__ combine)
{
    const int t = blockIdx.x;
    const int lane = threadIdx.x;
    float acc[kE] = {};
    for (int i = lane; i < kH; i += 64) {
        const float xv = h[(size_t)t * kH + i];
        const float* gw = gate_w + (size_t)i * kE;
        #pragma unroll
        for (int e = 0; e < kE; e++) acc[e] += xv * gw[e];
    }
    #pragma unroll
    for (int e = 0; e < kE; e++) {
        #pragma unroll
        for (int off = 32; off > 0; off >>= 1) acc[e] += __shfl_down(acc[e], off);
    }
    if (lane == 0) {
        float mx = acc[0];
        #pragma unroll
        for (int e = 1; e < kE; e++) mx = fmaxf(mx, acc[e]);
        float p[kE];
        float s = 0.0f;
        #pragma unroll
        for (int e = 0; e < kE; e++) { p[e] = expf(acc[e] - mx); s += p[e]; }
        const float invs = 1.0f / s;
        #pragma unroll
        for (int e = 0; e < kE; e++) p[e] *= invs;
        int i1 = 0;
        #pragma unroll
        for (int e = 1; e < kE; e++) if (p[e] > p[i1]) i1 = e;
        int i2 = (i1 == 0) ? 1 : 0;
        #pragma unroll
        for (int e = 0; e < kE; e++) if (e != i1 && p[e] > p[i2]) i2 = e;
        float outv[kE];
        #pragma unroll
        for (int e = 0; e < kE; e++) outv[e] = 0.0f;
        outv[i1] = p[i1];
        outv[i2] = p[i2];
        #pragma unroll
        for (int e = 0; e < kE; e++) combine[(size_t)t * kE + e] = outv[e];
    }
}

// ---------------------------------------------------------------------------
// Flash-style causal GQA attention, f32 compute, bf16 output.
// ---------------------------------------------------------------------------
constexpr int kAP = 68;

__global__ __launch_bounds__(256) void attn_kernel(
    const float* __restrict__ qkv, ushort* __restrict__ attn_o)
{
    __shared__ float Qs[64 * kAP];
    __shared__ float Ks[64 * kAP];
    __shared__ float Vs[64 * kAP];
    __shared__ float Ps[64 * kAP];
    __shared__ float alphaS[64];
    __shared__ float lS[64];
    const int tid = threadIdx.x;
    const int qb = blockIdx.x * 64;
    const int hq = blockIdx.y;
    const int kvh = hq >> 2;
    const int ldr = tid >> 2;
    const int ldd = (tid & 3) * 16;
    const int sr = tid >> 4;
    const int sc = tid & 15;
    const int mr = tid >> 2;
    const int mc = (tid & 3) * 16;

    {
        const float4* src = reinterpret_cast<const float4*>(
            qkv + (size_t)(qb + ldr) * kQKV + hq * kD + ldd);
        float4* dst = reinterpret_cast<float4*>(&Qs[ldr * kAP + ldd]);
        #pragma unroll
        for (int jj = 0; jj < 4; jj++) {
            float4 v = src[jj];
            v.x *= 0.125f; v.y *= 0.125f; v.z *= 0.125f; v.w *= 0.125f;
            dst[jj] = v;
        }
    }
    float oacc[4][4] = {};
    float m = -1e30f, l = 0.0f;

    for (int s0 = 0; s0 <= qb; s0 += 64) {
        __syncthreads();
        {
            const float4* ksrc = reinterpret_cast<const float4*>(
                qkv + (size_t)(s0 + ldr) * kQKV + (kNQ * kD) + kvh * kD + ldd);
            const float4* vsrc = reinterpret_cast<const float4*>(
                qkv + (size_t)(s0 + ldr) * kQKV + ((kNQ + kNKV) * kD) + kvh * kD + ldd);
            float4* kdst = reinterpret_cast<float4*>(&Ks[ldr * kAP + ldd]);
            float4* vdst = reinterpret_cast<float4*>(&Vs[ldr * kAP + ldd]);
            #pragma unroll
            for (int jj = 0; jj < 4; jj++) { kdst[jj] = ksrc[jj]; vdst[jj] = vsrc[jj]; }
        }
        __syncthreads();

        float sacc[4][4] = {};
        #pragma unroll
        for (int d4 = 0; d4 < 16; d4++) {
            float qv[4][4], kv[4][4];
            #pragma unroll
            for (int i = 0; i < 4; i++) {
                float4 q4 = *reinterpret_cast<const float4*>(&Qs[(sr * 4 + i) * kAP + d4 * 4]);
                qv[i][0] = q4.x; qv[i][1] = q4.y; qv[i][2] = q4.z; qv[i][3] = q4.w;
            }
            #pragma unroll
            for (int j = 0; j < 4; j++) {
                float4 k4 = *reinterpret_cast<const float4*>(&Ks[(sc * 4 + j) * kAP + d4 * 4]);
                kv[j][0] = k4.x; kv[j][1] = k4.y; kv[j][2] = k4.z; kv[j][3] = k4.w;
            }
            #pragma unroll
            for (int i = 0; i < 4; i++) {
                #pragma unroll
                for (int j = 0; j < 4; j++) {
                    float a = sacc[i][j];
                    #pragma unroll
                    for (int d = 0; d < 4; d++) a += qv[i][d] * kv[j][d];
                    sacc[i][j] = a;
                }
            }
        }
        #pragma unroll
        for (int i = 0; i < 4; i++) {
            const int trow = qb + sr * 4 + i;
            #pragma unroll
            for (int j = 0; j < 4; j++) {
                const int scol = s0 + sc * 4 + j;
                Ps[(sr * 4 + i) * kAP + sc * 4 + j] = (scol <= trow) ? sacc[i][j] : -1e30f;
            }
        }
        __syncthreads();

        float pv[16];
        float mloc = -1e30f;
        #pragma unroll
        for (int j4 = 0; j4 < 4; j4++) {
            float4 v4 = *reinterpret_cast<const float4*>(&Ps[mr * kAP + mc + j4 * 4]);
            pv[j4 * 4 + 0] = v4.x; pv[j4 * 4 + 1] = v4.y;
            pv[j4 * 4 + 2] = v4.z; pv[j4 * 4 + 3] = v4.w;
            mloc = fmaxf(mloc, fmaxf(fmaxf(v4.x, v4.y), fmaxf(v4.z, v4.w)));
        }
        mloc = fmaxf(mloc, __shfl_xor(mloc, 1));
        mloc = fmaxf(mloc, __shfl_xor(mloc, 2));
        const float mnew = fmaxf(m, mloc);
        const float alpha = __expf(m - mnew);
        float psum = 0.0f;
        #pragma unroll
        for (int j = 0; j < 16; j++) {
            const float p = __expf(pv[j] - mnew);
            pv[j] = p;
            psum += p;
        }
        psum += __shfl_xor(psum, 1);
        psum += __shfl_xor(psum, 2);
        l = l * alpha + psum;
        m = mnew;
        #pragma unroll
        for (int j4 = 0; j4 < 4; j4++) {
            *reinterpret_cast<float4*>(&Ps[mr * kAP + mc + j4 * 4]) =
                make_float4(pv[j4 * 4 + 0], pv[j4 * 4 + 1], pv[j4 * 4 + 2], pv[j4 * 4 + 3]);
        }
        if ((tid & 3) == 0) alphaS[mr] = alpha;
        __syncthreads();

        #pragma unroll
        for (int i = 0; i < 4; i++) {
            const float al = alphaS[sr * 4 + i];
            #pragma unroll
            for (int j = 0; j < 4; j++) oacc[i][j] *= al;
        }
        #pragma unroll
        for (int k4 = 0; k4 < 16; k4++) {
            float pvv[4][4], vvv[4][4];
            #pragma unroll
            for (int i = 0; i < 4; i++) {
                float4 p4 = *reinterpret_cast<const float4*>(&Ps[(sr * 4 + i) * kAP + k4 * 4]);
                pvv[i][0] = p4.x; pvv[i][1] = p4.y; pvv[i][2] = p4.z; pvv[i][3] = p4.w;
            }
            #pragma unroll
            for (int kk = 0; kk < 4; kk++) {
                float4 v4 = *reinterpret_cast<const float4*>(&Vs[(k4 * 4 + kk) * kAP + sc * 4]);
                vvv[kk][0] = v4.x; vvv[kk][1] = v4.y; vvv[kk][2] = v4.z; vvv[kk][3] = v4.w;
            }
            #pragma unroll
            for (int i = 0; i < 4; i++) {
                #pragma unroll
                for (int j = 0; j < 4; j++) {
                    float a = oacc[i][j];
                    #pragma unroll
                    for (int kk = 0; kk < 4; kk++) a += pvv[i][kk] * vvv[kk][j];
                    oacc[i][j] = a;
                }
            }
        }
    }

    if ((tid & 3) == 0) lS[mr] = l;
    __syncthreads();
    #pragma unroll
    for (int i = 0; i < 4; i++) {
        const float inv = 1.0f / lS[sr * 4 + i];
        ushort4 u;
        u.x = f2bf(oacc[i][0] * inv);
        u.y = f2bf(oacc[i][1] * inv);
        u.z = f2bf(oacc[i][2] * inv);
        u.w = f2bf(oacc[i][3] * inv);
        *reinterpret_cast<ushort4*>(
            &attn_o[(size_t)(qb + sr * 4 + i) * (kNQ * kD) + hq * kD + sc * 4]) = u;
    }
}

__global__ __launch_bounds__(256) void final_out_kernel(
    const float* __restrict__ mlp, const float* __restrict__ shortcut,
    const float* __restrict__ r, float* __restrict__ out)
{
    const int i = blockIdx.x * 256 + threadIdx.x;
    float4 a = reinterpret_cast<const float4*>(mlp)[i];
    float4 b = reinterpret_cast<const float4*>(shortcut)[i];
    reinterpret_cast<float4*>(out)[i] =
        make_float4(a.x + b.x, a.y + b.y, a.z + b.z, a.w + b.w);
    reinterpret_cast<float4*>(out + (size_t)kT * kH)[i] =
        reinterpret_cast<const float4*>(r)[i];
}

}  // namespace

extern "C" void kernel_launch(void* const* d_in, const int* in_sizes, int n_in,
                              void* d_out, int out_size, void* d_ws, size_t ws_size,
                              hipStream_t stream) {
    (void)in_sizes; (void)n_in; (void)out_size; (void)ws_size;
    const float* hidden   = (const float*)d_in[0];
    const float* residual = (const float*)d_in[1];
    const int*   positions= (const int*)d_in[2];
    const float* ln0_w    = (const float*)d_in[3];
    const float* pa0_w    = (const float*)d_in[4];
    const float* ln1_w    = (const float*)d_in[5];
    const float* pa1_w    = (const float*)d_in[6];
    const float* qkv0_w   = (const float*)d_in[7];
    const float* o0_w     = (const float*)d_in[8];
    const float* qkv1_w   = (const float*)d_in[9];
    const float* o1_w     = (const float*)d_in[10];
    const float* gu0_w    = (const float*)d_in[11];
    const float* dn0_w    = (const float*)d_in[12];
    const float* gu1_w    = (const float*)d_in[13];
    const float* dn1_w    = (const float*)d_in[14];
    const float* gate_w   = (const float*)d_in[15];
    const float* w13      = (const float*)d_in[16];
    const float* w2       = (const float*)d_in[17];
    float* out_h = (float*)d_out;

    char* wsb = (char*)d_ws;
    float*  r_buf   = (float*)(wsb + (0ull  << 20));   // 4 MB
    float*  h32     = (float*)(wsb + (4ull  << 20));   // 4 MB
    float*  t0_buf  = (float*)(wsb + (8ull  << 20));   // 4 MB
    float*  qkv_buf = (float*)(wsb + (12ull << 20));   // 6 MB
    float*  sc_buf  = (float*)(wsb + (18ull << 20));   // 4 MB
    float*  cb_buf  = (float*)(wsb + (22ull << 20));   // 32 KB
    ushort* h16     = (ushort*)(wsb + (23ull << 20));  // 2 MB
    ushort* ao16    = (ushort*)(wsb + (25ull << 20));  // 2 MB
    ushort* he16    = (ushort*)(wsb + (27ull << 20));  // 8 MB
    ushort* wT      = (ushort*)(wsb + (35ull << 20));  // 16 MB (ends at 51 MB)

    auto transp = [&](const float* W, int R, int Cn, int nz, long zs) {
        transpose_bf16_kernel<<<dim3(Cn / 64, R / 64, nz), 256, 0, stream>>>(
            W, wT, R, Cn, zs, zs);
    };
    auto gemm_f32 = [&](const ushort* A, float* C, int N, int lda_,
                        int ldb_, int ldc_, int nz, int kc, int kzoff, int atomic) {
        mgemm_kernel<false><<<dim3(N / 64, kT / 64, nz), 256, 0, stream>>>(
            A, wT, C, nullptr, nullptr, lda_, ldb_, ldc_, kc,
            0, 0, 0, kzoff, 0, atomic);
    };
    auto attention = [&](const float* qkv_w, const float* o_w) {
        transp(qkv_w, kH, kQKV, 1, 0);
        gemm_f32(h16, qkv_buf, kQKV, kH, kH, kQKV, 1, kH, 0, 0);
        rope_kernel<<<kT, 256, 0, stream>>>(qkv_buf, positions);
        attn_kernel<<<dim3(kT / 64, kNQ), 256, 0, stream>>>(qkv_buf, ao16);
        transp(o_w, kNQ * kD, kH, 1, 0);
        hipMemsetAsync(t0_buf, 0, (size_t)kT * kH * 4, stream);
        gemm_f32(ao16, t0_buf, kH, kNQ * kD, kNQ * kD, kH, 2, 512, 512, 1);
    };
    auto dense_mlp = [&](const float* gu_w, const float* dn_w) {
        transp(gu_w, kH, 2 * kIDense, 1, 0);
        mgemm_kernel<true><<<dim3(kIDense / 64, kT / 64, 1), 256, 0, stream>>>(
            h16, wT, nullptr, he16, nullptr, kH, kH, kIDense, kH,
            kIDense, 0, 0, 0, 0, 0);
        transp(dn_w, kIDense, kH, 1, 0);
        hipMemsetAsync(t0_buf, 0, (size_t)kT * kH * 4, stream);
        gemm_f32(he16, t0_buf, kH, kIDense, kIDense, kH, 4, 1024, 1024, 1);
    };

    // h, r = add_rmsnorm(hidden, residual, ln0)
    add_rmsnorm_kernel<<<kT, 256, 0, stream>>>(hidden, residual, ln0_w, h32, h16, r_buf);
    // h = attention0(h) -> t0
    attention(qkv0_w, o0_w);
    // h, r = add_rmsnorm(t0, r, pa0)
    add_rmsnorm_kernel<<<kT, 256, 0, stream>>>(t0_buf, r_buf, pa0_w, h32, h16, r_buf);
    // shortcut = moe(h)
    gate_topk_kernel<<<kT, 64, 0, stream>>>(h32, gate_w, cb_buf);
    transp(w13, kH, 2 * kIMoe, kE, (long)kH * 2 * kIMoe);
    mgemm_kernel<true><<<dim3(kIMoe / 64, kT / 64, kE), 256, 0, stream>>>(
        h16, wT, nullptr, he16, cb_buf, kH, kH, kIDense, kH,
        kIMoe, (long)kH * 2 * kIMoe, kIMoe, 0, kE, 0);
    transp(w2, kE * kIMoe, kH, 1, 0);
    hipMemsetAsync(sc_buf, 0, (size_t)kT * kH * 4, stream);
    gemm_f32(he16, sc_buf, kH, kIDense, kIDense, kH, 4, 1024, 1024, 1);
    // h = dense_mlp0(h) -> t0
    dense_mlp(gu0_w, dn0_w);
    // h, r = add_rmsnorm(t0, r, ln1)
    add_rmsnorm_kernel<<<kT, 256, 0, stream>>>(t0_buf, r_buf, ln1_w, h32, h16, r_buf);
    // h = attention1(h) -> t0
    attention(qkv1_w, o1_w);
    // h, r = add_rmsnorm(t0, r, pa1)
    add_rmsnorm_kernel<<<kT, 256, 0, stream>>>(t0_buf, r_buf, pa1_w, h32, h16, r_buf);
    // h = dense_mlp1(h) -> t0
    dense_mlp(gu1_w, dn1_w);
    // out = (t0 + shortcut, r)
    final_out_kernel<<<(kT * kH / 4) / 256, 256, 0, stream>>>(t0_buf, sc_buf, r_buf, out_h);
}

// Round 3
// 402.046 us; speedup vs baseline: 5.2854x; 1.9706x over previous
//
#include <hip/hip_runtime.h>
#include <math.h>

namespace {

constexpr int kT = 1024;
constexpr int kH = 1024;
constexpr int kNQ = 16;
constexpr int kNKV = 4;
constexpr int kD = 64;
constexpr int kQKV = (kNQ + 2 * kNKV) * kD;   // 1536
constexpr int kIDense = 4096;
constexpr int kIMoe = 512;
constexpr int kE = 8;
constexpr float kEps = 1e-6f;

typedef __attribute__((ext_vector_type(8))) short short8;
typedef __attribute__((ext_vector_type(4))) float f32x4;

__device__ __forceinline__ ushort f2bf(float f) {
    union { float f; uint32_t u; } v; v.f = f;
    uint32_t r = (v.u + 0x7fffu + ((v.u >> 16) & 1u)) >> 16;
    return (ushort)r;
}
__device__ __forceinline__ void gload16(const void* g, void* l) {
    __builtin_amdgcn_global_load_lds(
        (const __attribute__((address_space(1))) void*)g,
        (__attribute__((address_space(3))) void*)l, 16, 0, 0);
}

// ---------------------------------------------------------------------------
// add + RMSNorm: r_out = x + res; h = rmsnorm(r_out)*w  -> h32 (f32) + h16 (bf16)
// ---------------------------------------------------------------------------
__global__ __launch_bounds__(256) void add_rmsnorm_kernel(
    const float* __restrict__ x, const float* __restrict__ res,
    const float* __restrict__ w, float* __restrict__ h32,
    ushort* __restrict__ h16, float* __restrict__ r_out)
{
    __shared__ float red[4];
    const int t = blockIdx.x;
    const int i = threadIdx.x;
    const size_t base = (size_t)t * kH;
    float4 a = reinterpret_cast<const float4*>(x + base)[i];
    float4 b = reinterpret_cast<const float4*>(res + base)[i];
    float4 s = make_float4(a.x + b.x, a.y + b.y, a.z + b.z, a.w + b.w);
    reinterpret_cast<float4*>(r_out + base)[i] = s;
    float ss = s.x * s.x + s.y * s.y + s.z * s.z + s.w * s.w;
    #pragma unroll
    for (int off = 32; off > 0; off >>= 1) ss += __shfl_down(ss, off);
    if ((i & 63) == 0) red[i >> 6] = ss;
    __syncthreads();
    const float tot = red[0] + red[1] + red[2] + red[3];
    const float inv = rsqrtf(tot * (1.0f / kH) + kEps);
    float4 wv = reinterpret_cast<const float4*>(w)[i];
    float4 o = make_float4(s.x * inv * wv.x, s.y * inv * wv.y,
                           s.z * inv * wv.z, s.w * inv * wv.w);
    reinterpret_cast<float4*>(h32 + base)[i] = o;
    ushort4 u;
    u.x = f2bf(o.x); u.y = f2bf(o.y); u.z = f2bf(o.z); u.w = f2bf(o.w);
    reinterpret_cast<ushort4*>(h16 + base)[i] = u;
}

// ---------------------------------------------------------------------------
// transpose + f32 -> bf16: W (R x Cn f32, row stride ld_w) -> WT (Cn x R bf16)
// 64x64 tiles; batched via blockIdx.z.
// ---------------------------------------------------------------------------
__global__ __launch_bounds__(256) void transpose_bf16_kernel(
    const float* __restrict__ W, ushort* __restrict__ WT,
    int R, int Cn, int ld_w, long w_z_stride, long wt_z_stride)
{
    __shared__ float tile[64][65];
    const int z = blockIdx.z;
    const float* Wz = W + (size_t)z * w_z_stride;
    ushort* WTz = WT + (size_t)z * wt_z_stride;
    const int r0 = blockIdx.y * 64;
    const int c0 = blockIdx.x * 64;
    const int tr = threadIdx.x >> 4;
    const int tc4 = (threadIdx.x & 15) * 4;
    #pragma unroll
    for (int p = 0; p < 4; p++) {
        float4 v = *reinterpret_cast<const float4*>(
            &Wz[(size_t)(r0 + p * 16 + tr) * ld_w + c0 + tc4]);
        tile[p * 16 + tr][tc4 + 0] = v.x;
        tile[p * 16 + tr][tc4 + 1] = v.y;
        tile[p * 16 + tr][tc4 + 2] = v.z;
        tile[p * 16 + tr][tc4 + 3] = v.w;
    }
    __syncthreads();
    #pragma unroll
    for (int p = 0; p < 4; p++) {
        const int oc = p * 16 + tr;          // input col = output row
        ushort4 u;
        u.x = f2bf(tile[tc4 + 0][oc]);
        u.y = f2bf(tile[tc4 + 1][oc]);
        u.z = f2bf(tile[tc4 + 2][oc]);
        u.w = f2bf(tile[tc4 + 3][oc]);
        *reinterpret_cast<ushort4*>(&WTz[(size_t)(c0 + oc) * R + r0 + tc4]) = u;
    }
}

// ---------------------------------------------------------------------------
// bf16 MFMA GEMM, 64x64 tile, BK=64, 256 threads (4 waves, 2x2 16x16 frags).
// A: M x lda bf16 row-major. B: N x ldb bf16 row-major (i.e. weight^T).
// ---------------------------------------------------------------------------
template <bool GATED>
__global__ __launch_bounds__(256) void mgemm_kernel(
    const ushort* __restrict__ A, const ushort* __restrict__ B,
    float* __restrict__ Cf, ushort* __restrict__ C16,
    const float* __restrict__ scale,
    int lda, int ldb, int ldc, int kc,
    int gate_off_rows, long b_z_stride, int c_z_col, int k_z_off,
    int scale_stride, int atomic_flag)
{
    __shared__ __align__(16) ushort As[64 * 64];
    __shared__ __align__(16) ushort Bs[64 * 64];
    __shared__ __align__(16) ushort Us[GATED ? 64 * 64 : 16];

    const int z = blockIdx.z;
    const int m0 = blockIdx.y * 64;
    const int n0 = blockIdx.x * 64;
    const int tid = threadIdx.x;
    const ushort* Bz = B + (size_t)z * b_z_stride;
    const int k0 = z * k_z_off;

    const int srow = tid >> 3;
    const int sc8 = (tid & 7) * 8;

    const int lane = tid & 63;
    const int wave = tid >> 6;
    const int wr = (wave >> 1) * 32;
    const int wc = (wave & 1) * 32;
    const int lrow = lane & 15;
    const int lk8 = (lane >> 4) * 8;

    f32x4 accg[2][2] = {};
    f32x4 accu[2][2] = {};

    for (int kk0 = 0; kk0 < kc; kk0 += 64) {
        const int kbase = k0 + kk0;
        #pragma unroll
        for (int i = 0; i < 2; i++) {
            gload16(A + (size_t)(m0 + i * 32 + srow) * lda + kbase + sc8,
                    (char*)As + i * 4096 + tid * 16);
            gload16(Bz + (size_t)(n0 + i * 32 + srow) * ldb + kbase + sc8,
                    (char*)Bs + i * 4096 + tid * 16);
            if constexpr (GATED)
                gload16(Bz + (size_t)(gate_off_rows + n0 + i * 32 + srow) * ldb + kbase + sc8,
                        (char*)Us + i * 4096 + tid * 16);
        }
        __syncthreads();

        short8 af[2][2], bfr[2][2];
        #pragma unroll
        for (int mf = 0; mf < 2; mf++)
            #pragma unroll
            for (int kk = 0; kk < 2; kk++)
                af[mf][kk] = *reinterpret_cast<const short8*>(
                    &As[(wr + mf * 16 + lrow) * 64 + kk * 32 + lk8]);
        #pragma unroll
        for (int nf = 0; nf < 2; nf++)
            #pragma unroll
            for (int kk = 0; kk < 2; kk++)
                bfr[nf][kk] = *reinterpret_cast<const short8*>(
                    &Bs[(wc + nf * 16 + lrow) * 64 + kk * 32 + lk8]);
        #pragma unroll
        for (int mf = 0; mf < 2; mf++)
            #pragma unroll
            for (int nf = 0; nf < 2; nf++)
                #pragma unroll
                for (int kk = 0; kk < 2; kk++)
                    accg[mf][nf] = __builtin_amdgcn_mfma_f32_16x16x32_bf16(
                        af[mf][kk], bfr[nf][kk], accg[mf][nf], 0, 0, 0);
        if constexpr (GATED) {
            short8 uf[2][2];
            #pragma unroll
            for (int nf = 0; nf < 2; nf++)
                #pragma unroll
                for (int kk = 0; kk < 2; kk++)
                    uf[nf][kk] = *reinterpret_cast<const short8*>(
                        &Us[(wc + nf * 16 + lrow) * 64 + kk * 32 + lk8]);
            #pragma unroll
            for (int mf = 0; mf < 2; mf++)
                #pragma unroll
                for (int nf = 0; nf < 2; nf++)
                    #pragma unroll
                    for (int kk = 0; kk < 2; kk++)
                        accu[mf][nf] = __builtin_amdgcn_mfma_f32_16x16x32_bf16(
                            af[mf][kk], uf[nf][kk], accu[mf][nf], 0, 0, 0);
        }
        __syncthreads();
    }

    const int r4 = (lane >> 4) * 4;
    const int cl = lane & 15;
    const int ccol = z * c_z_col;
    #pragma unroll
    for (int mf = 0; mf < 2; mf++) {
        #pragma unroll
        for (int nf = 0; nf < 2; nf++) {
            #pragma unroll
            for (int j = 0; j < 4; j++) {
                const int row = m0 + wr + mf * 16 + r4 + j;
                const int col = ccol + n0 + wc + nf * 16 + cl;
                if constexpr (GATED) {
                    const float g = accg[mf][nf][j];
                    const float u = accu[mf][nf][j];
                    const float sv =
                        scale ? scale[(size_t)row * scale_stride + z] : 1.0f;
                    const float h = (g / (1.0f + __expf(-g))) * u * sv;
                    C16[(size_t)row * ldc + col] = f2bf(h);
                } else if (atomic_flag) {
                    atomicAdd(&Cf[(size_t)row * ldc + col], accg[mf][nf][j]);
                } else {
                    Cf[(size_t)row * ldc + col] = accg[mf][nf][j];
                }
            }
        }
    }
}

// ---------------------------------------------------------------------------
// RoPE + bf16 pack: reads f32 qkv rows, writes Qb [16][T][64] (scaled by
// D^-0.5) and Kb [4][T][64], both bf16.
// ---------------------------------------------------------------------------
__global__ __launch_bounds__(256) void rope_pack_kernel(
    const float* __restrict__ qkv, const int* __restrict__ positions,
    ushort* __restrict__ Qb, ushort* __restrict__ Kb)
{
    const int t = blockIdx.x;
    const float pos = (float)positions[t];
    for (int item = threadIdx.x; item < (kNQ + kNKV) * 32; item += 256) {
        const int head = item >> 5;
        const int i = item & 31;
        const float inv_freq = powf(10000.0f, -(float)i * (1.0f / 32.0f));
        const float f = pos * inv_freq;
        float sv, cv;
        sincosf(f, &sv, &cv);
        const size_t off = (size_t)t * kQKV + head * kD;
        const float x1 = qkv[off + i];
        const float x2 = qkv[off + 32 + i];
        const float r1 = x1 * cv - x2 * sv;
        const float r2 = x2 * cv + x1 * sv;
        if (head < kNQ) {
            ushort* q = Qb + ((size_t)head * kT + t) * kD;
            q[i] = f2bf(r1 * 0.125f);
            q[i + 32] = f2bf(r2 * 0.125f);
        } else {
            ushort* k = Kb + ((size_t)(head - kNQ) * kT + t) * kD;
            k[i] = f2bf(r1);
            k[i + 32] = f2bf(r2);
        }
    }
}

// ---------------------------------------------------------------------------
// Router: logits = h32 @ gate_w, softmax, top-2 -> combine (T x 8)
// ---------------------------------------------------------------------------
__global__ __launch_bounds__(64) void gate_topk_kernel(
    const float* __restrict__ h, const float* __restrict__ gate_w,
    float* __restrict__ combine)
{
    const int t = blockIdx.x;
    const int lane = threadIdx.x;
    float acc[kE] = {};
    for (int i = lane; i < kH; i += 64) {
        const float xv = h[(size_t)t * kH + i];
        const float* gw = gate_w + (size_t)i * kE;
        #pragma unroll
        for (int e = 0; e < kE; e++) acc[e] += xv * gw[e];
    }
    #pragma unroll
    for (int e = 0; e < kE; e++) {
        #pragma unroll
        for (int off = 32; off > 0; off >>= 1) acc[e] += __shfl_down(acc[e], off);
    }
    if (lane == 0) {
        float mx = acc[0];
        #pragma unroll
        for (int e = 1; e < kE; e++) mx = fmaxf(mx, acc[e]);
        float p[kE];
        float s = 0.0f;
        #pragma unroll
        for (int e = 0; e < kE; e++) { p[e] = expf(acc[e] - mx); s += p[e]; }
        const float invs = 1.0f / s;
        #pragma unroll
        for (int e = 0; e < kE; e++) p[e] *= invs;
        int i1 = 0;
        #pragma unroll
        for (int e = 1; e < kE; e++) if (p[e] > p[i1]) i1 = e;
        int i2 = (i1 == 0) ? 1 : 0;
        #pragma unroll
        for (int e = 0; e < kE; e++) if (e != i1 && p[e] > p[i2]) i2 = e;
        float outv[kE];
        #pragma unroll
        for (int e = 0; e < kE; e++) outv[e] = 0.0f;
        outv[i1] = p[i1];
        outv[i2] = p[i2];
        #pragma unroll
        for (int e = 0; e < kE; e++) combine[(size_t)t * kE + e] = outv[e];
    }
}

// ---------------------------------------------------------------------------
// MFMA flash attention. Block = (64 q-rows, 1 q-head), 4 waves.
// S^T = mfma(K,Q) so each lane owns one q-row's softmax (shfl_xor 16/32).
// P relayout via per-wave 16-row LDS strip. All LDS XOR-swizzled:
// byte ^= (row&7)<<4 within each 128B row; staging applies the inverse
// swizzle on the GLOBAL source (global_load_lds dest must stay linear).
// ---------------------------------------------------------------------------
__global__ __launch_bounds__(256) void attn_mfma_kernel(
    const ushort* __restrict__ Qb, const ushort* __restrict__ Kb,
    const ushort* __restrict__ Vt, ushort* __restrict__ attn_o)
{
    __shared__ __align__(16) ushort Qs[64 * 64];
    __shared__ __align__(16) ushort Ks[64 * 64];
    __shared__ __align__(16) ushort Vs[64 * 64];
    __shared__ __align__(16) ushort Ps[64 * 64];
    const int tid = threadIdx.x;
    const int qb = blockIdx.x * 64;
    const int hq = blockIdx.y;
    const int kvh = hq >> 2;
    const int lane = tid & 63;
    const int wave = tid >> 6;
    const int lrow = lane & 15;
    const int g = lane >> 4;
    const int srow = tid >> 3;          // staging row 0..31 per chunk
    const int sx = tid & 7;             // staging 16B slot
    const ushort* Qg = Qb + ((size_t)hq * kT + qb) * kD;
    const ushort* Kg = Kb + (size_t)kvh * kT * kD;
    const ushort* Vg = Vt + (size_t)kvh * kD * kT;   // [d][t]
    const int xr = (lrow & 7) << 4;     // read-side XOR (row = ...+lrow)

    #pragma unroll
    for (int c = 0; c < 2; c++) {
        const int row = c * 32 + srow;
        gload16(Qg + (size_t)row * kD + ((sx ^ (row & 7)) * 8),
                (char*)Qs + c * 4096 + tid * 16);
    }
    __syncthreads();
    short8 qf[2];
    #pragma unroll
    for (int kk = 0; kk < 2; kk++)
        qf[kk] = *reinterpret_cast<const short8*>(
            (const char*)Qs + (16 * wave + lrow) * 128 + ((kk * 64 + g * 16) ^ xr));

    f32x4 oacc[4] = {};
    float mrow = -1e30f, lsum = 0.0f;

    for (int s0 = 0; s0 <= qb; s0 += 64) {
        __syncthreads();
        #pragma unroll
        for (int c = 0; c < 2; c++) {
            const int row = c * 32 + srow;
            gload16(Kg + (size_t)(s0 + row) * kD + ((sx ^ (row & 7)) * 8),
                    (char*)Ks + c * 4096 + tid * 16);
            gload16(Vg + (size_t)row * kT + s0 + ((sx ^ (row & 7)) * 8),
                    (char*)Vs + c * 4096 + tid * 16);
        }
        __syncthreads();

        // S^T[kv][m]: A-frags = K rows, B-frags = this wave's Q rows
        f32x4 sacc[4] = {};
        #pragma unroll
        for (int nf = 0; nf < 4; nf++) {
            #pragma unroll
            for (int kk = 0; kk < 2; kk++) {
                short8 kf = *reinterpret_cast<const short8*>(
                    (const char*)Ks + (nf * 16 + lrow) * 128 + ((kk * 64 + g * 16) ^ xr));
                sacc[nf] = __builtin_amdgcn_mfma_f32_16x16x32_bf16(
                    kf, qf[kk], sacc[nf], 0, 0, 0);
            }
        }

        // lane owns q-row m = 16*wave + lrow; its 16 kv values: nf*16+4g+j
        const bool diag = (s0 == qb);
        float pv[16];
        float mloc = -1e30f;
        #pragma unroll
        for (int nf = 0; nf < 4; nf++)
            #pragma unroll
            for (int j = 0; j < 4; j++) {
                float s = sacc[nf][j];
                if (diag && (nf * 16 + g * 4 + j > 16 * wave + lrow)) s = -1e30f;
                pv[nf * 4 + j] = s;
                mloc = fmaxf(mloc, s);
            }
        mloc = fmaxf(mloc, __shfl_xor(mloc, 16));
        mloc = fmaxf(mloc, __shfl_xor(mloc, 32));
        const float mnew = fmaxf(mrow, mloc);
        const float alpha = __expf(mrow - mnew);
        float psum = 0.0f;
        #pragma unroll
        for (int j = 0; j < 16; j++) { pv[j] = __expf(pv[j] - mnew); psum += pv[j]; }
        psum += __shfl_xor(psum, 16);
        psum += __shfl_xor(psum, 32);
        lsum = lsum * alpha + psum;
        mrow = mnew;

        // P -> LDS (bf16 pairs), swizzled; wave-local strip (rows 16w..16w+15)
        const int prow = 16 * wave + lrow;
        #pragma unroll
        for (int nf = 0; nf < 4; nf++)
            #pragma unroll
            for (int jp = 0; jp < 2; jp++) {
                uint32_t pk = (uint32_t)f2bf(pv[nf * 4 + jp * 2]) |
                              ((uint32_t)f2bf(pv[nf * 4 + jp * 2 + 1]) << 16);
                *reinterpret_cast<uint32_t*>(
                    (char*)Ps + prow * 128 + ((nf * 32 + g * 8 + jp * 4) ^ xr)) = pk;
            }

        // rescale O (alpha for O's rows 4g+j lives in lane 4g+j)
        float aj[4];
        #pragma unroll
        for (int j = 0; j < 4; j++) aj[j] = __shfl(alpha, g * 4 + j);
        #pragma unroll
        for (int nf = 0; nf < 4; nf++)
            #pragma unroll
            for (int j = 0; j < 4; j++) oacc[nf][j] *= aj[j];

        // O += P @ V : A-frags from Ps (this wave's rows), B-frags from Vs
        short8 paf[2];
        #pragma unroll
        for (int kk = 0; kk < 2; kk++)
            paf[kk] = *reinterpret_cast<const short8*>(
                (const char*)Ps + prow * 128 + ((kk * 64 + g * 16) ^ xr));
        #pragma unroll
        for (int nf = 0; nf < 4; nf++)
            #pragma unroll
            for (int kk = 0; kk < 2; kk++) {
                short8 vf = *reinterpret_cast<const short8*>(
                    (const char*)Vs + (nf * 16 + lrow) * 128 + ((kk * 64 + g * 16) ^ xr));
                oacc[nf] = __builtin_amdgcn_mfma_f32_16x16x32_bf16(
                    paf[kk], vf, oacc[nf], 0, 0, 0);
            }
    }

    float lj[4];
    #pragma unroll
    for (int j = 0; j < 4; j++) lj[j] = 1.0f / __shfl(lsum, g * 4 + j);
    #pragma unroll
    for (int nf = 0; nf < 4; nf++)
        #pragma unroll
        for (int j = 0; j < 4; j++) {
            const int trow = qb + 16 * wave + g * 4 + j;
            attn_o[(size_t)trow * (kNQ * kD) + hq * kD + nf * 16 + lrow] =
                f2bf(oacc[nf][j] * lj[j]);
        }
}

__global__ __launch_bounds__(256) void final_out_kernel(
    const float* __restrict__ mlp, const float* __restrict__ shortcut,
    const float* __restrict__ r, float* __restrict__ out)
{
    const int i = blockIdx.x * 256 + threadIdx.x;
    float4 a = reinterpret_cast<const float4*>(mlp)[i];
    float4 b = reinterpret_cast<const float4*>(shortcut)[i];
    reinterpret_cast<float4*>(out)[i] =
        make_float4(a.x + b.x, a.y + b.y, a.z + b.z, a.w + b.w);
    reinterpret_cast<float4*>(out + (size_t)kT * kH)[i] =
        reinterpret_cast<const float4*>(r)[i];
}

}  // namespace

extern "C" void kernel_launch(void* const* d_in, const int* in_sizes, int n_in,
                              void* d_out, int out_size, void* d_ws, size_t ws_size,
                              hipStream_t stream) {
    (void)in_sizes; (void)n_in; (void)out_size; (void)ws_size;
    const float* hidden   = (const float*)d_in[0];
    const float* residual = (const float*)d_in[1];
    const int*   positions= (const int*)d_in[2];
    const float* ln0_w    = (const float*)d_in[3];
    const float* pa0_w    = (const float*)d_in[4];
    const float* ln1_w    = (const float*)d_in[5];
    const float* pa1_w    = (const float*)d_in[6];
    const float* qkv0_w   = (const float*)d_in[7];
    const float* o0_w     = (const float*)d_in[8];
    const float* qkv1_w   = (const float*)d_in[9];
    const float* o1_w     = (const float*)d_in[10];
    const float* gu0_w    = (const float*)d_in[11];
    const float* dn0_w    = (const float*)d_in[12];
    const float* gu1_w    = (const float*)d_in[13];
    const float* dn1_w    = (const float*)d_in[14];
    const float* gate_w   = (const float*)d_in[15];
    const float* w13      = (const float*)d_in[16];
    const float* w2       = (const float*)d_in[17];
    float* out_h = (float*)d_out;

    char* wsb = (char*)d_ws;
    float*  r_buf   = (float*)(wsb + (0ull  << 20));   // 4 MB
    float*  h32     = (float*)(wsb + (4ull  << 20));   // 4 MB
    float*  t0_buf  = (float*)(wsb + (8ull  << 20));   // 4 MB
    float*  qkv_buf = (float*)(wsb + (12ull << 20));   // 6 MB
    float*  sc_buf  = (float*)(wsb + (18ull << 20));   // 4 MB
    float*  cb_buf  = (float*)(wsb + (22ull << 20));   // 32 KB
    ushort* h16     = (ushort*)(wsb + (23ull << 20));  // 2 MB
    ushort* ao16    = (ushort*)(wsb + (25ull << 20));  // 2 MB
    ushort* he16    = (ushort*)(wsb + (27ull << 20));  // 8 MB
    ushort* wT      = (ushort*)(wsb + (35ull << 20));  // 16 MB (ends 51 MB)
    // attn bf16 buffers alias the tail of wT (lifetime-disjoint: only live
    // between rope_pack and attn_mfma, when wT holds only qkv_w^T [3 MB])
    ushort* Qb      = (ushort*)(wsb + (40ull << 20));  // 2 MB
    ushort* Kb      = (ushort*)(wsb + (42ull << 20));  // 0.5 MB
    ushort* VtG     = (ushort*)(wsb + (43ull << 20));  // 0.5 MB

    auto transp = [&](const float* W, int R, int Cn, int nz, long zs) {
        transpose_bf16_kernel<<<dim3(Cn / 64, R / 64, nz), 256, 0, stream>>>(
            W, wT, R, Cn, Cn, zs, zs);
    };
    auto gemm_f32 = [&](const ushort* A, float* C, int N, int lda_,
                        int ldb_, int ldc_, int nz, int kc, int kzoff, int atomic) {
        mgemm_kernel<false><<<dim3(N / 64, kT / 64, nz), 256, 0, stream>>>(
            A, wT, C, nullptr, nullptr, lda_, ldb_, ldc_, kc,
            0, 0, 0, kzoff, 0, atomic);
    };
    auto attention = [&](const float* qkv_w, const float* o_w) {
        transp(qkv_w, kH, kQKV, 1, 0);
        gemm_f32(h16, qkv_buf, kQKV, kH, kH, kQKV, 1, kH, 0, 0);
        rope_pack_kernel<<<kT, 256, 0, stream>>>(qkv_buf, positions, Qb, Kb);
        // V^T: per head h, transpose qkv[:, 1280+64h : +64] -> VtG[h][64][1024]
        transpose_bf16_kernel<<<dim3(1, kT / 64, kNKV), 256, 0, stream>>>(
            qkv_buf + (kNQ + kNKV) * kD, VtG, kT, kD, kQKV, kD, (long)kD * kT);
        attn_mfma_kernel<<<dim3(kT / 64, kNQ), 256, 0, stream>>>(Qb, Kb, VtG, ao16);
        transp(o_w, kNQ * kD, kH, 1, 0);
        hipMemsetAsync(t0_buf, 0, (size_t)kT * kH * 4, stream);
        gemm_f32(ao16, t0_buf, kH, kNQ * kD, kNQ * kD, kH, 2, 512, 512, 1);
    };
    auto dense_mlp = [&](const float* gu_w, const float* dn_w) {
        transp(gu_w, kH, 2 * kIDense, 1, 0);
        mgemm_kernel<true><<<dim3(kIDense / 64, kT / 64, 1), 256, 0, stream>>>(
            h16, wT, nullptr, he16, nullptr, kH, kH, kIDense, kH,
            kIDense, 0, 0, 0, 0, 0);
        transp(dn_w, kIDense, kH, 1, 0);
        hipMemsetAsync(t0_buf, 0, (size_t)kT * kH * 4, stream);
        gemm_f32(he16, t0_buf, kH, kIDense, kIDense, kH, 4, 1024, 1024, 1);
    };

    // h, r = add_rmsnorm(hidden, residual, ln0)
    add_rmsnorm_kernel<<<kT, 256, 0, stream>>>(hidden, residual, ln0_w, h32, h16, r_buf);
    // h = attention0(h) -> t0
    attention(qkv0_w, o0_w);
    // h, r = add_rmsnorm(t0, r, pa0)
    add_rmsnorm_kernel<<<kT, 256, 0, stream>>>(t0_buf, r_buf, pa0_w, h32, h16, r_buf);
    // shortcut = moe(h)
    gate_topk_kernel<<<kT, 64, 0, stream>>>(h32, gate_w, cb_buf);
    transp(w13, kH, 2 * kIMoe, kE, (long)kH * 2 * kIMoe);
    mgemm_kernel<true><<<dim3(kIMoe / 64, kT / 64, kE), 256, 0, stream>>>(
        h16, wT, nullptr, he16, cb_buf, kH, kH, kIDense, kH,
        kIMoe, (long)kH * 2 * kIMoe, kIMoe, 0, kE, 0);
    transp(w2, kE * kIMoe, kH, 1, 0);
    hipMemsetAsync(sc_buf, 0, (size_t)kT * kH * 4, stream);
    gemm_f32(he16, sc_buf, kH, kIDense, kIDense, kH, 4, 1024, 1024, 1);
    // h = dense_mlp0(h) -> t0
    dense_mlp(gu0_w, dn0_w);
    // h, r = add_rmsnorm(t0, r, ln1)
    add_rmsnorm_kernel<<<kT, 256, 0, stream>>>(t0_buf, r_buf, ln1_w, h32, h16, r_buf);
    // h = attention1(h) -> t0
    attention(qkv1_w, o1_w);
    // h, r = add_rmsnorm(t0, r, pa1)
    add_rmsnorm_kernel<<<kT, 256, 0, stream>>>(t0_buf, r_buf, pa1_w, h32, h16, r_buf);
    // h = dense_mlp1(h) -> t0
    dense_mlp(gu1_w, dn1_w);
    // out = (t0 + shortcut, r)
    final_out_kernel<<<(kT * kH / 4) / 256, 256, 0, stream>>>(t0_buf, sc_buf, r_buf, out_h);
}